// Round 3
// 6181.324 us; speedup vs baseline: 1.3419x; 1.3419x over previous
//
#include <hip/hip_runtime.h>
#include <stdint.h>

#define NB 64
#define NT 512
#define NH 512

typedef short bf8 __attribute__((ext_vector_type(8)));   // 8 bf16 vals (4 VGPRs)
typedef float f4  __attribute__((ext_vector_type(4)));

static __device__ __forceinline__ float bf2f(uint16_t u) {
  union { uint32_t i; float f; } v; v.i = ((uint32_t)u) << 16; return v.f;
}
static __device__ __forceinline__ uint16_t f2bf(float f) {
  union { float f; uint32_t i; } v; v.f = f;
  uint32_t r = v.i + 0x7fffu + ((v.i >> 16) & 1u);
  return (uint16_t)(r >> 16);
}

__global__ void k_f2bf(const float* __restrict__ src, uint16_t* __restrict__ dst, int n4) {
  int i = blockIdx.x * 256 + threadIdx.x;
  if (i < n4) {
    float4 v = ((const float4*)src)[i];
    uint16_t* d = dst + (size_t)i * 4;
    d[0] = f2bf(v.x); d[1] = f2bf(v.y); d[2] = f2bf(v.z); d[3] = f2bf(v.w);
  }
}

// rows permuted: row' = u*4+gate  <-  row = gate*512 + u ; fp32 -> bf16
__global__ void k_wperm(const float* __restrict__ src, uint16_t* __restrict__ dst, int K) {
  int rp = blockIdx.x;
  int row = (rp & 3) * NH + (rp >> 2);
  const float* s = src + (size_t)row * K;
  uint16_t* d = dst + (size_t)rp * K;
  for (int k = threadIdx.x; k < K; k += 256) d[k] = f2bf(s[k]);
}

__global__ void k_bperm(const float* __restrict__ src, float* __restrict__ dst) {
  int rp = blockIdx.x * 256 + threadIdx.x;
  if (rp < 2048) {
    int row = (rp & 3) * NH + (rp >> 2);
    dst[rp] = src[row];
  }
}

// C[m=b*T+t][n] = A[m][:] . W[n][:]  + bias[n], written bf16 to xg[t][b][n&2047]
template<int K>
__global__ __launch_bounds__(256, 2)
void k_gemm(const uint16_t* __restrict__ A, const uint16_t* __restrict__ W,
            const float* __restrict__ bias,
            uint16_t* __restrict__ xg_f, uint16_t* __restrict__ xg_b) {
  __shared__ __align__(16) uint16_t lds[2][2][8][512];   // 32 KB
  const int tid = threadIdx.x;
  const int w = tid >> 6, lane = tid & 63;
  const int quad = lane >> 4, nIdx = lane & 15;
  const int bn = blockIdx.x, bm = blockIdx.y;
  const int wm = w >> 1, wn = w & 1;
  constexpr int KS = K / 32;

  f4 acc[4][4];
  #pragma unroll
  for (int i = 0; i < 4; ++i)
    #pragma unroll
    for (int j = 0; j < 4; ++j)
      #pragma unroll
      for (int q = 0; q < 4; ++q) acc[i][j][q] = 0.f;

  const size_t arow0 = (size_t)(bm * 128 + nIdx) * K + quad * 8;
  const size_t brow0 = (size_t)(bn * 128 + nIdx) * K + quad * 8;

  #pragma unroll
  for (int cc = 0; cc < 2; ++cc) {
    int mt = w + cc * 4;
    bf8 va = *(const bf8*)(A + arow0 + (size_t)mt * 16 * K);
    bf8 vb = *(const bf8*)(W + brow0 + (size_t)mt * 16 * K);
    *(bf8*)&lds[0][0][mt][lane * 8] = va;
    *(bf8*)&lds[0][1][mt][lane * 8] = vb;
  }
  for (int ks = 0; ks < KS; ++ks) {
    __syncthreads();
    bf8 va[2], vb[2];
    const bool pre = (ks + 1 < KS);
    if (pre) {
      #pragma unroll
      for (int cc = 0; cc < 2; ++cc) {
        int mt = w + cc * 4;
        va[cc] = *(const bf8*)(A + arow0 + (size_t)mt * 16 * K + (ks + 1) * 32);
        vb[cc] = *(const bf8*)(W + brow0 + (size_t)mt * 16 * K + (ks + 1) * 32);
      }
    }
    const int buf = ks & 1;
    bf8 af[4], bg[4];
    #pragma unroll
    for (int i = 0; i < 4; ++i) af[i] = *(const bf8*)&lds[buf][0][wm * 4 + i][lane * 8];
    #pragma unroll
    for (int j = 0; j < 4; ++j) bg[j] = *(const bf8*)&lds[buf][1][wn * 4 + j][lane * 8];
    #pragma unroll
    for (int i = 0; i < 4; ++i)
      #pragma unroll
      for (int j = 0; j < 4; ++j)
        acc[i][j] = __builtin_amdgcn_mfma_f32_16x16x32_bf16(af[i], bg[j], acc[i][j], 0, 0, 0);
    if (pre) {
      #pragma unroll
      for (int cc = 0; cc < 2; ++cc) {
        int mt = w + cc * 4;
        *(bf8*)&lds[buf ^ 1][0][mt][lane * 8] = va[cc];
        *(bf8*)&lds[buf ^ 1][1][mt][lane * 8] = vb[cc];
      }
    }
  }
  #pragma unroll
  for (int i = 0; i < 4; ++i) {
    int mbase = bm * 128 + (wm * 4 + i) * 16 + quad * 4;
    #pragma unroll
    for (int r = 0; r < 4; ++r) {
      int mm = mbase + r;
      int bb = mm >> 9, tt = mm & 511;
      size_t rowoff = ((size_t)tt * 64 + bb) * 2048;
      #pragma unroll
      for (int j = 0; j < 4; ++j) {
        int n = bn * 128 + (wn * 4 + j) * 16 + nIdx;
        float v = acc[i][j][r] + bias[n];
        uint16_t* dst = (n < 2048) ? xg_f : xg_b;
        dst[rowoff + (n & 2047)] = f2bf(v);
      }
    }
  }
}

// Persistent recurrence. grid = 64 blocks: dir = blk>>5, wg = blk&31 owns
// rows' [wg*64, wg*64+64) = units [wg*16, wg*16+16).
//
// Sync protocol = round-0 proven skeleton, verbatim: producers h -> hT (LDS
// transpose) -> coalesced 128x16B global_store sc0 sc1 -> vmcnt drain ->
// flag[s][wg]=s+1 (plain coherent store). Consumers: wave0 polls the 32
// flags (signed >=, poison-safe), barrier, then 16x global_load_dwordx4
// sc0 sc1 staged into padded LDS, MFMA. y-stores + xg prefetch sit after
// the flag publish (off critical path).
//
// NEW vs round 0: M/N-swapped MFMA. D[w_row][batch] = mfma(Wfrag, hfrag).
// With the gate-interleaved weight permutation (row' = 4u+gate), C-layout
// row=quad*4+reg puts i,f,g,o of unit u = wg*16+w*4+quad in one lane's 4
// acc regs, batch = nt*16+nIdx. Gate math is fully lane-local: no
// __shfl_xor chains, no cross-gate selects, 4x less cell math per lane.
template<bool FINAL>
__global__ __launch_bounds__(256, 1)
void k_recur(const uint16_t* __restrict__ xg_f, const uint16_t* __restrict__ xg_b,
             const uint16_t* __restrict__ WhP, const int* __restrict__ lens,
             uint16_t* __restrict__ hbuf, int* __restrict__ flags,
             uint16_t* __restrict__ y0, float* __restrict__ dout, int layer) {
  __shared__ __align__(16) uint16_t hlds[64 * 520];   // staging: 64 x (512+8) u16
  __shared__ __align__(16) uint16_t hT[64 * 40];      // h transpose tile: rows bb, stride 40
  const int tid = threadIdx.x;
  const int w = tid >> 6, lane = tid & 63;
  const int quad = lane >> 4, nIdx = lane & 15;
  const int dir = blockIdx.x >> 5, wg = blockIdx.x & 31;
  const int mrow = wg * 64 + w * 16 + nIdx;   // weight row' for A-fragment
  const int u = wg * 16 + w * 4 + quad;       // this lane's hidden unit
  const int u_local = w * 4 + quad;           // 0..15 within this WG's tile
  const uint16_t* xg = dir ? xg_b : xg_f;
  const uint16_t* Wrow = WhP + ((size_t)dir * 2048 + mrow) * 512;
  bf8 bfr[16];
  #pragma unroll
  for (int kt = 0; kt < 16; ++kt) bfr[kt] = *(const bf8*)(Wrow + kt * 32 + quad * 8);
  float c[4], h[4];
  int len[4];
  #pragma unroll
  for (int nt = 0; nt < 4; ++nt) {
    c[nt] = 0.f; h[nt] = 0.f; len[nt] = lens[nt * 16 + nIdx];
  }
  int* flg = flags + dir * 512 * 32;
  uint16_t* hb = hbuf + (size_t)dir * 2 * NB * NH;
  const uint32_t voff = (uint32_t)(w * 512 + lane * 8) * 2;   // staging-load byte offset

  // prefetch xg for step 0: 4 gates of unit u are 4 consecutive u16
  ushort4 xgp[4];
  {
    const int t0 = dir ? 511 : 0;
    #pragma unroll
    for (int nt = 0; nt < 4; ++nt)
      xgp[nt] = *(const ushort4*)(xg + ((size_t)t0 * 64 + nt * 16 + nIdx) * 2048 + u * 4);
  }

  for (int s = 0; s < 512; ++s) {
    const int t = dir ? (511 - s) : s;
    f4 acc[4];
    #pragma unroll
    for (int nt = 0; nt < 4; ++nt)
      #pragma unroll
      for (int q = 0; q < 4; ++q) acc[nt][q] = 0.f;
    if (s > 0) {
      if (w == 0) {
        const int* fp = flg + (s - 1) * 32 + (lane & 31);
        while (true) {
          int v = __hip_atomic_load(fp, __ATOMIC_RELAXED, __HIP_MEMORY_SCOPE_AGENT);
          if (__all(v >= s)) break;     // poison 0xAAAAAAAA is negative -> safe
          __builtin_amdgcn_s_sleep(1);
        }
      }
      __syncthreads();
      // ---- stage h (64x512 bf16) via coherence-point loads ----
      const uint16_t* hr = hb + ((s + 1) & 1) * (NB * NH);
      bf8 tmp[16];
      #pragma unroll
      for (int i = 0; i < 16; ++i) {
        const uint16_t* p = hr + i * 2048;   // uniform saddr; voff = per-thread bytes
        asm volatile("global_load_dwordx4 %0, %1, %2 sc0 sc1"
                     : "=v"(tmp[i]) : "v"(voff), "s"(p) : "memory");
      }
      asm volatile("s_waitcnt vmcnt(0)" ::: "memory");
      #pragma unroll
      for (int i = 0; i < 16; ++i) {
        *(bf8*)&hlds[(i * 4 + w) * 520 + lane * 8] = tmp[i];
      }
      __syncthreads();
      // ---- MFMA: acc[nt] += W(M=weight-row') x h(N=batch) ----
      #pragma unroll
      for (int nt = 0; nt < 4; ++nt) {
        const uint16_t* hrow = &hlds[(nt * 16 + nIdx) * 520 + quad * 8];
        #pragma unroll
        for (int kt = 0; kt < 16; ++kt)
          acc[nt] = __builtin_amdgcn_mfma_f32_16x16x32_bf16(
              bfr[kt], *(const bf8*)(hrow + kt * 32), acc[nt], 0, 0, 0);
      }
    }
    // ---- gates: lane-local i,f,g,o per (u, batch=nt*16+nIdx) ----
    float yv[4];
    #pragma unroll
    for (int nt = 0; nt < 4; ++nt) {
      const int bb = nt * 16 + nIdx;
      float g0 = acc[nt][0] + bf2f(xgp[nt].x);
      float g1 = acc[nt][1] + bf2f(xgp[nt].y);
      float g2 = acc[nt][2] + bf2f(xgp[nt].z);
      float g3 = acc[nt][3] + bf2f(xgp[nt].w);
      float iv = 1.f / (1.f + __expf(-g0));
      float fv = 1.f / (1.f + __expf(-g1));
      float eg = __expf(2.f * g2); float gv = 1.f - 2.f / (eg + 1.f);
      float ov = 1.f / (1.f + __expf(-g3));
      float cn = fv * c[nt] + iv * gv;
      float e2 = __expf(2.f * cn); float th = 1.f - 2.f / (e2 + 1.f);
      float hn = ov * th;
      bool valid = (t < len[nt]);
      float cnew = valid ? cn : c[nt];
      float hnew = valid ? hn : h[nt];
      c[nt] = cnew; h[nt] = hnew;
      yv[nt] = valid ? hn : 0.f;
      hT[bb * 40 + u_local] = f2bf(hnew);   // LDS transpose (distinct addr per lane)
    }
    __syncthreads();   // hT complete (all waves)
    // ---- coalesced h publish: threads 0..127 store 16B each (2 KB total) ----
    if (tid < 128) {
      uint16_t* hw = hb + (s & 1) * (NB * NH);
      const int bb = tid >> 1, half = tid & 1;
      bf8 hv = *(const bf8*)&hT[bb * 40 + half * 8];
      uint32_t vo2 = (uint32_t)bb * 1024 + (uint32_t)wg * 32 + (uint32_t)half * 16;
      asm volatile("global_store_dwordx4 %0, %1, %2 sc0 sc1"
                   :: "v"(vo2), "v"(hv), "s"(hw) : "memory");
      asm volatile("s_waitcnt vmcnt(0)" ::: "memory");   // h acked at coherence point
    }
    __syncthreads();   // all h stores acked
    if (tid == 0) {
      uint32_t fo = (uint32_t)(s * 32 + wg) * 4;
      uint32_t fv = (uint32_t)(s + 1);
      asm volatile("global_store_dword %0, %1, %2 sc0 sc1"
                   :: "v"(fo), "v"(fv), "s"(flg) : "memory");
    }
    // ---- off-critical-path: y stores + xg prefetch (overlap the spin) ----
    #pragma unroll
    for (int nt = 0; nt < 4; ++nt) {
      const int bb = nt * 16 + nIdx;
      size_t yo = ((size_t)bb * 512 + t) * 1024 + (size_t)dir * 512 + u;
      if (FINAL) __builtin_nontemporal_store(yv[nt], &dout[yo]);
      else       __builtin_nontemporal_store(f2bf(yv[nt]), &y0[yo]);
    }
    {
      const int sp = (s + 1 < 512) ? (s + 1) : 511;
      const int t2 = dir ? (511 - sp) : sp;
      #pragma unroll
      for (int nt = 0; nt < 4; ++nt)
        xgp[nt] = *(const ushort4*)(xg + ((size_t)t2 * 64 + nt * 16 + nIdx) * 2048 + u * 4);
    }
  }
  // final hN/cN: each lane owns 4 unique (batch, u) pairs
  {
    const size_t HN = 33554432, CN = 33554432 + 131072;
    int slot = layer * 2 + dir;
    #pragma unroll
    for (int nt = 0; nt < 4; ++nt) {
      int bb = nt * 16 + nIdx;
      dout[HN + ((size_t)slot * 64 + bb) * 512 + u] = h[nt];
      dout[CN + ((size_t)slot * 64 + bb) * 512 + u] = c[nt];
    }
  }
}

extern "C" void kernel_launch(void* const* d_in, const int* in_sizes, int n_in,
                              void* d_out, int out_size, void* d_ws, size_t ws_size,
                              hipStream_t stream) {
  (void)in_sizes; (void)n_in; (void)out_size; (void)ws_size;
  const float* x     = (const float*)d_in[0];
  const int*   lens  = (const int*)d_in[1];
  const float* Wi_f0 = (const float*)d_in[2];
  const float* Wh_f0 = (const float*)d_in[3];
  const float* b_f0  = (const float*)d_in[4];
  const float* Wi_b0 = (const float*)d_in[5];
  const float* Wh_b0 = (const float*)d_in[6];
  const float* b_b0  = (const float*)d_in[7];
  const float* Wi_f1 = (const float*)d_in[8];
  const float* Wh_f1 = (const float*)d_in[9];
  const float* b_f1  = (const float*)d_in[10];
  const float* Wi_b1 = (const float*)d_in[11];
  const float* Wh_b1 = (const float*)d_in[12];
  const float* b_b1  = (const float*)d_in[13];
  float* out = (float*)d_out;
  char* ws = (char*)d_ws;

  const size_t BIAS0 = 8192, BIAS1 = 24576;   // fp32 [4096] each
  const size_t HBUF = 40960;                  // bf16 [2][2][64][512] = 256 KB
  const size_t XBF   = 303104;                // bf16 x: 32 MB
  const size_t Y0    = XBF + 33554432;        // bf16 y0 [64][512][1024]: 64 MB
  const size_t WCAT0 = Y0 + 67108864;         // bf16 [4096][512]
  const size_t WCAT1 = WCAT0 + 4194304;       // bf16 [4096][1024]
  const size_t WHP0  = WCAT1 + 8388608;       // bf16 [2][2048][512]
  const size_t WHP1  = WHP0 + 4194304;
  const size_t XGF   = WHP1 + 4194304;        // bf16 [512][64][2048]: 128 MB
  const size_t XGB   = XGF + 134217728;       // 128 MB
  const size_t FLAGS = XGB + 134217728;       // int[2 layers][2 dirs][512][32] = 256 KB

  float* bias0    = (float*)(ws + BIAS0);
  float* bias1    = (float*)(ws + BIAS1);
  uint16_t* hbuf  = (uint16_t*)(ws + HBUF);
  uint16_t* xbf   = (uint16_t*)(ws + XBF);
  uint16_t* y0    = (uint16_t*)(ws + Y0);
  uint16_t* wcat0 = (uint16_t*)(ws + WCAT0);
  uint16_t* wcat1 = (uint16_t*)(ws + WCAT1);
  uint16_t* whp0  = (uint16_t*)(ws + WHP0);
  uint16_t* whp1  = (uint16_t*)(ws + WHP1);
  uint16_t* xgf   = (uint16_t*)(ws + XGF);
  uint16_t* xgb   = (uint16_t*)(ws + XGB);
  int* flags      = (int*)(ws + FLAGS);

  k_f2bf<<<16384, 256, 0, stream>>>(x, xbf, 4194304);
  k_wperm<<<2048, 256, 0, stream>>>(Wi_f0, wcat0, 512);
  k_wperm<<<2048, 256, 0, stream>>>(Wi_b0, wcat0 + 2048 * 512, 512);
  k_wperm<<<2048, 256, 0, stream>>>(Wi_f1, wcat1, 1024);
  k_wperm<<<2048, 256, 0, stream>>>(Wi_b1, wcat1 + (size_t)2048 * 1024, 1024);
  k_wperm<<<2048, 256, 0, stream>>>(Wh_f0, whp0, 512);
  k_wperm<<<2048, 256, 0, stream>>>(Wh_b0, whp0 + 2048 * 512, 512);
  k_wperm<<<2048, 256, 0, stream>>>(Wh_f1, whp1, 512);
  k_wperm<<<2048, 256, 0, stream>>>(Wh_b1, whp1 + 2048 * 512, 512);
  k_bperm<<<8, 256, 0, stream>>>(b_f0, bias0);
  k_bperm<<<8, 256, 0, stream>>>(b_b0, bias0 + 2048);
  k_bperm<<<8, 256, 0, stream>>>(b_f1, bias1);
  k_bperm<<<8, 256, 0, stream>>>(b_b1, bias1 + 2048);

  k_gemm<512><<<dim3(32, 256), 256, 0, stream>>>(xbf, wcat0, bias0, xgf, xgb);
  k_recur<false><<<64, 256, 0, stream>>>(xgf, xgb, whp0, lens, hbuf, flags, y0, out, 0);
  k_gemm<1024><<<dim3(32, 256), 256, 0, stream>>>(y0, wcat1, bias1, xgf, xgb);
  k_recur<true><<<64, 256, 0, stream>>>(xgf, xgb, whp1, lens, hbuf, flags + 2 * 512 * 32, y0, out, 1);
}